// Round 12
// baseline (158.198 us; speedup 1.0000x reference)
//
#include <hip/hip_runtime.h>
#include <hip/hip_bf16.h>
#include <math.h>

#define N_NODES 10000
#define N_EDGES 160000
#define DIN 128
#define DW 512
#define NHEAD 8
#define NC 64
#define MPAD 10112     // 79 * 128
#define GEMM_BLKS 316  // 79 * 4

typedef unsigned short ushort_t;
typedef __attribute__((ext_vector_type(8))) short bf16x8;
typedef __attribute__((ext_vector_type(8))) unsigned short us8;
typedef __attribute__((ext_vector_type(4))) float f32x4;

__device__ inline ushort_t f2bf(float v) {
    unsigned u = __builtin_bit_cast(unsigned, v);
    return (ushort_t)((u + 0x7fff + ((u >> 16) & 1)) >> 16);
}
__device__ inline float bf2f(ushort_t h) {
    return __builtin_bit_cast(float, (unsigned)h << 16);
}

// swizzled tile-major index: tiles of 128 rows x 64 k, 8192 ushort each.
__device__ __forceinline__ size_t swz_idx(int rb, int r, int kp, int nkt) {
    int kt = kp >> 6, kc = kp & 63;
    return ((size_t)(rb * nkt + kt)) * 8192 + r * 64 + (kc ^ ((r & 7) << 3));
}

__device__ __forceinline__ void gld16(const ushort_t* g, ushort_t* l) {
    __builtin_amdgcn_global_load_lds(
        (const __attribute__((address_space(1))) void*)g,
        (__attribute__((address_space(3))) void*)l, 16, 0, 0);
}

// ================= merged prep: prepx(vec) + prepWft + prepW1 + zero =================
__global__ void k_prep(const float* __restrict__ x, const float* __restrict__ ftW,
                       const float* __restrict__ W1f,
                       ushort_t* __restrict__ Ax, ushort_t* __restrict__ Bx,
                       ushort_t* __restrict__ B1,
                       int* __restrict__ cnt, int* __restrict__ cursor) {
    int bid = blockIdx.x, t = threadIdx.x;
    if (bid < 632) {                        // prepx: Ax[MPAD][256] = [xhi | xlo], 16B stores
        int gid = bid * 256 + t;            // n * 16 + chunk
        int n = gid >> 4, k0 = (gid & 15) * 8;
        float v[8];
        if (n < N_NODES) {
            #pragma unroll
            for (int u = 0; u < 8; u++) v[u] = x[n * DIN + k0 + u];
        } else {
            #pragma unroll
            for (int u = 0; u < 8; u++) v[u] = 0.f;
        }
        us8 hi, lo;
        #pragma unroll
        for (int u = 0; u < 8; u++) {
            ushort_t h = f2bf(v[u]);
            hi[u] = h;
            lo[u] = f2bf(v[u] - bf2f(h));
        }
        int rb = n >> 7, r = n & 127;
        *(us8*)(Ax + swz_idx(rb, r, k0, 4)) = hi;
        *(us8*)(Ax + swz_idx(rb, r, 128 + k0, 4)) = lo;
    } else if (bid < 888) {                 // prepWft: Bx[512][256] = [Whi | Whi]
        int i = (bid - 632) * 256 + t;
        int n = i >> 7, k = i & 127;
        ushort_t h = f2bf(ftW[k * DW + n]);
        int cb = n >> 7, rc = n & 127;
        Bx[swz_idx(cb, rc, k, 4)] = h;
        Bx[swz_idx(cb, rc, 128 + k, 4)] = h;
    } else if (bid < 1912) {                // prepW1: B1[512][1024] = [W1hi | W1hi]
        int i = (bid - 888) * 256 + t;
        int n = i >> 9, k = i & 511;
        ushort_t h = f2bf(W1f[k * DW + n]);
        int cb = n >> 7, rc = n & 127;
        B1[swz_idx(cb, rc, k, 16)] = h;
        B1[swz_idx(cb, rc, 512 + k, 16)] = h;
    } else {                                // zero cnt/cursor
        int i = (bid - 1912) * 256 + t;
        if (i < N_NODES) { cnt[i] = 0; cursor[i] = 0; }
    }
}

// ================= LDS-DMA double-buffered bf16 MFMA GEMM, 8 waves (+side work) =================
template<int KT, bool ATT, int EXTRA>
__global__ __launch_bounds__(512, 4) void k_tgemm(const ushort_t* __restrict__ A,
                                                  const ushort_t* __restrict__ Bm,
                                                  float* __restrict__ C,
                                                  ushort_t* __restrict__ Cb,
                                                  const float* __restrict__ asrc,
                                                  const float* __restrict__ adst,
                                                  float* __restrict__ aS,
                                                  float* __restrict__ aD,
                                                  const int* __restrict__ ei,
                                                  int* __restrict__ cnt,
                                                  const int* __restrict__ off,
                                                  int* __restrict__ cursor,
                                                  int* __restrict__ csrc) {
    __shared__ __align__(16) ushort_t As[2][8192];
    __shared__ __align__(16) ushort_t Bs[2][8192];
    int bid = blockIdx.x;
    if (bid >= GEMM_BLKS) {                 // ---- CSR side work ----
        int e = (bid - GEMM_BLKS) * 512 + threadIdx.x;
        if (e < N_EDGES) {
            if (EXTRA == 1) {
                atomicAdd(&cnt[ei[N_EDGES + e]], 1);
            } else {
                int d = ei[N_EDGES + e];
                int p = off[d] + atomicAdd(&cursor[d], 1);
                csrc[p] = ei[e];
            }
        }
        return;
    }
    int bx = bid >> 2, by = bid & 3;
    int t = threadIdx.x, w = t >> 6, l = t & 63;
    int lm = l & 15, g = l >> 4;
    int wr = w >> 1, wc = w & 1;            // 4 row-stripes x 2 col-stripes
    int rowbase = bx * 128;
    int colbase = by * 128;

    const ushort_t* Abase = A + (size_t)bx * KT * 8192 + t * 8;
    const ushort_t* Bbase = Bm + (size_t)by * KT * 8192 + t * 8;

    f32x4 acc[2][4];
    #pragma unroll
    for (int r = 0; r < 2; r++)
        #pragma unroll
        for (int c = 0; c < 4; c++) acc[r][c] = (f32x4){0.f, 0.f, 0.f, 0.f};

    {   // prologue: tile 0 -> buf 0 (4 DMA/thread)
        #pragma unroll
        for (int j = 0; j < 2; ++j) {
            gld16(Abase + j * 4096, &As[0][j * 4096 + t * 8]);
            gld16(Bbase + j * 4096, &Bs[0][j * 4096 + t * 8]);
        }
    }

    int p = 0;
    for (int kt = 0; kt < KT; ++kt) {
        __builtin_amdgcn_s_barrier();       // all waves done reading buf[p^1]
        if (kt + 1 < KT) {
            const ushort_t* ga = Abase + (size_t)(kt + 1) * 8192;
            const ushort_t* gb = Bbase + (size_t)(kt + 1) * 8192;
            #pragma unroll
            for (int j = 0; j < 2; ++j) {
                gld16(ga + j * 4096, &As[p ^ 1][j * 4096 + t * 8]);
                gld16(gb + j * 4096, &Bs[p ^ 1][j * 4096 + t * 8]);
            }
            asm volatile("s_waitcnt vmcnt(4)" ::: "memory");   // tile kt landed
        } else {
            asm volatile("s_waitcnt vmcnt(0)" ::: "memory");
        }
        __builtin_amdgcn_s_barrier();       // ALL waves' tile-kt DMA complete
        const char* Ap = (const char*)As[p];
        const char* Bp = (const char*)Bs[p];
        #pragma unroll
        for (int ks = 0; ks < 2; ++ks) {
            bf16x8 af[2], bfr[4];
            #pragma unroll
            for (int r = 0; r < 2; ++r) {
                int row = wr * 32 + r * 16 + lm;
                af[r] = *(const bf16x8*)(Ap + row * 128 +
                                         ((ks * 64 + g * 16) ^ ((row & 7) << 4)));
            }
            #pragma unroll
            for (int c = 0; c < 4; ++c) {
                int col = wc * 64 + c * 16 + lm;
                bfr[c] = *(const bf16x8*)(Bp + col * 128 +
                                          ((ks * 64 + g * 16) ^ ((col & 7) << 4)));
            }
            #pragma unroll
            for (int r = 0; r < 2; ++r)
                #pragma unroll
                for (int c = 0; c < 4; ++c)
                    acc[r][c] = __builtin_amdgcn_mfma_f32_16x16x32_bf16(af[r], bfr[c], acc[r][c], 0, 0, 0);
        }
        p ^= 1;
    }

    // C/D map: col = lane&15, row = (lane>>4)*4 + q
    if (!ATT) {
        #pragma unroll
        for (int r = 0; r < 2; ++r) {
            int row0 = rowbase + wr * 32 + r * 16 + g * 4;
            #pragma unroll
            for (int c = 0; c < 4; ++c) {
                int col = colbase + wc * 64 + c * 16 + lm;
                #pragma unroll
                for (int q = 0; q < 4; ++q)
                    if (row0 + q < N_NODES) C[(size_t)(row0 + q) * DW + col] = acc[r][c][q];
            }
        }
    } else {
        int h = 2 * by + wc;                  // this wave's head
        float asv[4], adv[4];
        #pragma unroll
        for (int c = 0; c < 4; ++c) {
            asv[c] = asrc[h * NC + c * 16 + lm];
            adv[c] = adst[h * NC + c * 16 + lm];
        }
        #pragma unroll
        for (int r = 0; r < 2; ++r) {
            int row0 = rowbase + wr * 32 + r * 16 + g * 4;
            #pragma unroll
            for (int c = 0; c < 4; ++c) {
                int col = colbase + wc * 64 + c * 16 + lm;
                #pragma unroll
                for (int q = 0; q < 4; ++q)
                    if (row0 + q < N_NODES) Cb[(size_t)(row0 + q) * DW + col] = f2bf(acc[r][c][q]);
            }
            #pragma unroll
            for (int q = 0; q < 4; ++q) {
                float ss = acc[r][0][q] * asv[0] + acc[r][1][q] * asv[1] +
                           acc[r][2][q] * asv[2] + acc[r][3][q] * asv[3];
                float dd = acc[r][0][q] * adv[0] + acc[r][1][q] * adv[1] +
                           acc[r][2][q] * adv[2] + acc[r][3][q] * adv[3];
                #pragma unroll
                for (int m = 1; m < 16; m <<= 1) {
                    ss += __shfl_xor(ss, m, 64);
                    dd += __shfl_xor(dd, m, 64);
                }
                int row = row0 + q;
                if (lm == 0 && row < N_NODES) {
                    aS[row * NHEAD + h] = ss;
                    aD[row * NHEAD + h] = dd;
                }
            }
        }
    }
}

// ================= LN epilogue -> h0big[*][1024] = [hi | lo], vectorized (+ scan block) =================
__global__ __launch_bounds__(256) void k_ln_scan(const float* __restrict__ hpre,
                                                 const float* __restrict__ fb,
                                                 const float* __restrict__ g,
                                                 const float* __restrict__ beta,
                                                 ushort_t* __restrict__ h0big,
                                                 const int* __restrict__ cnt,
                                                 int* __restrict__ off) {
    __shared__ int ps[256];
    __shared__ float red[8];
    __shared__ __align__(16) ushort_t st[1024];
    int bid = blockIdx.x, t = threadIdx.x;
    if (bid == MPAD) {                       // ---- exclusive scan over cnt ----
        int base = t * 40;
        int loc[40];
        int s = 0;
        #pragma unroll
        for (int i = 0; i < 40; i++) {
            int idx = base + i;
            int v = idx < N_NODES ? cnt[idx] : 0;
            loc[i] = s; s += v;
        }
        ps[t] = s; __syncthreads();
        for (int o = 1; o < 256; o <<= 1) {
            int v = (t >= o) ? ps[t - o] : 0;
            __syncthreads();
            ps[t] += v;
            __syncthreads();
        }
        int pre = (t > 0) ? ps[t - 1] : 0;
        #pragma unroll
        for (int i = 0; i < 40; i++) {
            int idx = base + i;
            if (idx < N_NODES) off[idx] = pre + loc[i];
        }
        if (t == 255) off[N_NODES] = ps[255];
        return;
    }
    int n = bid;
    int rb = n >> 7, r = n & 127;
    if (n >= N_NODES) {
        if (t < 128) {
            int kp0 = t * 8;
            *(us8*)(h0big + swz_idx(rb, r, kp0, 16)) = (us8){0,0,0,0,0,0,0,0};
        }
        return;
    }
    float a0 = hpre[(size_t)n * DW + t] + fb[t];
    float a1 = hpre[(size_t)n * DW + t + 256] + fb[t + 256];
    float s = a0 + a1, sq = a0 * a0 + a1 * a1;
    for (int o = 32; o > 0; o >>= 1) { s += __shfl_down(s, o, 64); sq += __shfl_down(sq, o, 64); }
    int wid = t >> 6;
    if ((t & 63) == 0) { red[wid] = s; red[4 + wid] = sq; }
    __syncthreads();
    if (t == 0) {
        float ts = red[0] + red[1] + red[2] + red[3];
        float tq = red[4] + red[5] + red[6] + red[7];
        float mu = ts / DW;
        float var = tq / DW - mu * mu;
        red[0] = mu; red[1] = rsqrtf(var + 1e-5f);
    }
    __syncthreads();
    float mu = red[0], rs = red[1];
    float v0 = (a0 - mu) * rs * g[t] + beta[t];
    float v1 = (a1 - mu) * rs * g[t + 256] + beta[t + 256];
    v0 = v0 >= 0.f ? v0 : 0.2f * v0;
    v1 = v1 >= 0.f ? v1 : 0.2f * v1;
    ushort_t h0_ = f2bf(v0), l0_ = f2bf(v0 - bf2f(h0_));
    ushort_t h1_ = f2bf(v1), l1_ = f2bf(v1 - bf2f(h1_));
    st[t] = h0_;        st[256 + t] = h1_;      // hi occupies kp 0..511
    st[512 + t] = l0_;  st[768 + t] = l1_;      // lo occupies kp 512..1023
    __syncthreads();
    if (t < 128) {
        int kp0 = t * 8;
        *(us8*)(h0big + swz_idx(rb, r, kp0, 16)) = *(const us8*)(st + kp0);
    }
}

// ================= layer-1 aggregation, head-sliced (XCD-L2-resident gather) =================
// Block (ng, h): h = bid & 7 -> all blocks of head h land on one XCD (round-robin
// dispatch), whose L2 then holds only slice h of h1b (1.25 MB). 8 nodes/block,
// 8 edge-slots x 32 lanes (2 cols each). Fused bias+BN+ReLU -> bf16 h2 slice.
__global__ __launch_bounds__(256) void k_agg1slice(
    const int* __restrict__ csrc, const int* __restrict__ off,
    const ushort_t* __restrict__ h1b,
    const float* __restrict__ aS, const float* __restrict__ aD,
    const float* __restrict__ b1, const float* __restrict__ bnm,
    const float* __restrict__ bnv, const float* __restrict__ bng,
    const float* __restrict__ bnb, ushort_t* __restrict__ h2b)
{
    int bid = blockIdx.x, t = threadIdx.x;
    int h = bid & 7, ng = bid >> 3;
    int lane32 = t & 31, slot = t >> 5;     // 8 edge-slots
    int j = h * NC + lane32 * 2;            // this thread's 2 columns
    // hoist BN/bias params (uniform per block-column)
    float b10 = b1[j], b11 = b1[j + 1];
    float sc0 = rsqrtf(bnv[j] + 1e-5f) * bng[j];
    float sc1 = rsqrtf(bnv[j + 1] + 1e-5f) * bng[j + 1];
    float mn0 = bnm[j], mn1 = bnm[j + 1];
    float bb0 = bnb[j], bb1 = bnb[j + 1];
    __shared__ float red[8][32][2];
    __shared__ float dred[8];
    for (int i = 0; i < 8; i++) {
        int n = ng * 8 + i;
        int beg = off[n], end = off[n + 1];
        float adn = aD[n * NHEAD + h];
        float acc0 = 0.f, acc1 = 0.f, den = 0.f;
        for (int c = beg + slot; c < end; c += 8) {   // 8 edges in flight per block
            int src = csrc[c];                         // broadcast within slot
            float l = aS[src * NHEAD + h] + adn;       // broadcast
            l = l >= 0.f ? l : 0.2f * l;
            float w = __expf(l);
            den += w;
            unsigned v = *(const unsigned*)(h1b + (size_t)src * DW + j);  // 128B/slot
            acc0 += w * __builtin_bit_cast(float, v << 16);
            acc1 += w * __builtin_bit_cast(float, v & 0xffff0000u);
        }
        if (slot) { red[slot][lane32][0] = acc0; red[slot][lane32][1] = acc1; }
        if (lane32 == 0) dred[slot] = den;
        __syncthreads();
        if (slot == 0) {
            #pragma unroll
            for (int s = 1; s < 8; s++) { acc0 += red[s][lane32][0]; acc1 += red[s][lane32][1]; }
            float dtot = dred[0] + dred[1] + dred[2] + dred[3] +
                         dred[4] + dred[5] + dred[6] + dred[7];
            float rd = dtot > 0.f ? 1.f / dtot : 0.f;
            float v0 = (acc0 * rd + b10 - mn0) * sc0 + bb0;
            v0 = v0 > 0.f ? v0 : 0.f;
            float v1 = (acc1 * rd + b11 - mn1) * sc1 + bb1;
            v1 = v1 > 0.f ? v1 : 0.f;
            unsigned pk = (unsigned)f2bf(v0) | ((unsigned)f2bf(v1) << 16);
            *(unsigned*)(h2b + (size_t)n * DW + j) = pk;
        }
        __syncthreads();
    }
}

// ================= GEMM2 + fused att2 (from h2 bf16) =================
__global__ __launch_bounds__(256) void k_gemm2att(const ushort_t* __restrict__ h2b,
                                                  const float* __restrict__ W2,
                                                  const float* __restrict__ as2,
                                                  const float* __restrict__ ad2,
                                                  float* __restrict__ gout,
                                                  float* __restrict__ aS,
                                                  float* __restrict__ aD) {
    __shared__ float Ws[DW * 16];
    __shared__ float gl[16][16];
    __shared__ float a2[32];
    int t = threadIdx.x;
    for (int i = t; i < DW * 16; i += 256) Ws[i] = W2[i];
    if (t < 16) a2[t] = as2[t];
    else if (t < 32) a2[t] = ad2[t - 16];
    __syncthreads();
    int nb = blockIdx.x * 16;
    int nl = t >> 4, j = t & 15;
    const bf16x8* hr = (const bf16x8*)(h2b + (size_t)(nb + nl) * DW);
    float acc = 0.f;
    for (int ks = 0; ks < DW / 8; ks++) {
        bf16x8 v = hr[ks];
        #pragma unroll
        for (int u = 0; u < 8; u++)
            acc += bf2f((ushort_t)v[u]) * Ws[(ks * 8 + u) * 16 + j];
    }
    gout[(nb + nl) * 16 + j] = acc;
    gl[nl][j] = acc;
    __syncthreads();
    if (j < 8) {
        aS[(nb + nl) * NHEAD + j] = gl[nl][2 * j] * a2[2 * j] + gl[nl][2 * j + 1] * a2[2 * j + 1];
    } else {
        int h = j - 8;
        aD[(nb + nl) * NHEAD + h] = gl[nl][2 * h] * a2[16 + 2 * h] + gl[nl][2 * h + 1] * a2[16 + 2 * h + 1];
    }
}

// ================= layer-2 aggregation, CSR, fused head-mean + b2 =================
__global__ __launch_bounds__(256) void k_agg2csr(
    const int* __restrict__ csrc, const int* __restrict__ off,
    const float* __restrict__ gbuf,
    const float* __restrict__ aS, const float* __restrict__ aD,
    const float* __restrict__ b2, float* __restrict__ outp)
{
    int t = threadIdx.x;
    int n = blockIdx.x * 4 + (t >> 6);
    int lane = t & 63;
    if (n >= N_NODES) return;
    int beg = off[n], end = off[n + 1];
    int j = lane & 15, slot = lane >> 4, h = j >> 1;
    float adn = aD[n * NHEAD + h];
    float acc = 0.f, den = 0.f;
    for (int c = beg + slot; c < end; c += 4) {
        int s = csrc[c];
        float l = aS[s * NHEAD + h] + adn;
        l = l >= 0.f ? l : 0.2f * l;
        float w = __expf(l);
        den += w;
        acc += w * gbuf[s * 16 + j];
    }
    acc += __shfl_down(acc, 16, 64); acc += __shfl_down(acc, 32, 64);
    den += __shfl_down(den, 16, 64); den += __shfl_down(den, 32, 64);
    float v = (lane < 16 && den > 0.f) ? acc / den : 0.f;
    v += __shfl_down(v, 2, 64);
    v += __shfl_down(v, 4, 64);
    v += __shfl_down(v, 8, 64);
    if (lane < 2) outp[n * 2 + lane] = v * 0.125f + b2[lane];
}

extern "C" void kernel_launch(void* const* d_in, const int* in_sizes, int n_in,
                              void* d_out, int out_size, void* d_ws, size_t ws_size,
                              hipStream_t stream) {
    const float* x    = (const float*)d_in[0];
    const int*   ei   = (const int*)d_in[1];
    const float* ftW  = (const float*)d_in[2];
    const float* ftb  = (const float*)d_in[3];
    const float* lng  = (const float*)d_in[4];
    const float* lnb  = (const float*)d_in[5];
    const float* W1   = (const float*)d_in[6];
    const float* as1  = (const float*)d_in[7];
    const float* ad1  = (const float*)d_in[8];
    const float* b1   = (const float*)d_in[9];
    const float* bng  = (const float*)d_in[10];
    const float* bnb  = (const float*)d_in[11];
    const float* bnm  = (const float*)d_in[12];
    const float* bnv  = (const float*)d_in[13];
    const float* W2   = (const float*)d_in[14];
    const float* as2  = (const float*)d_in[15];
    const float* ad2  = (const float*)d_in[16];
    const float* b2   = (const float*)d_in[17];
    float* out = (float*)d_out;

    // ---- workspace (float offsets), lifetime-aliased, ~60.2 MB ----
    float* F = (float*)d_ws;
    ushort_t* Ax    = (ushort_t*)(F + 0);          // dead after ft GEMM
    float*    gbuf  = F + 0;                       // 160,000 f
    ushort_t* Bx    = (ushort_t*)(F + 1294336);
    ushort_t* B1    = (ushort_t*)(F + 1359872);
    float*    hpre  = F + 1622016;                 // dead after LN
    ushort_t* h2b   = (ushort_t*)(F + 1622016);    // written by agg1slice
    ushort_t* h0big = (ushort_t*)(F + 6799360);
    ushort_t* h1b   = (ushort_t*)(F + 11976704);
    float*    aS1   = F + 14536704;
    float*    aD1   = F + 14616704;
    float*    aS2   = F + 14696704;
    float*    aD2   = F + 14776704;
    int* cnt        = (int*)(F + 14856704);
    int* cursor     = (int*)(F + 14866704);
    int* off        = (int*)(F + 14876704);
    int* csrc       = (int*)(F + 14886705);

    // 1. merged prep (Ax-vec + Bx + B1 + zero)
    k_prep<<<1952, 256, 0, stream>>>(x, ftW, W1, Ax, Bx, B1, cnt, cursor);
    // 2. ft GEMM (K'=256) + CSR count
    k_tgemm<4, false, 1><<<GEMM_BLKS + 313, 512, 0, stream>>>(
        Ax, Bx, hpre, nullptr, nullptr, nullptr, nullptr, nullptr,
        ei, cnt, nullptr, nullptr, nullptr);
    // 3. LN -> h0big (K'=1024 [hi|lo], vectorized) + CSR scan
    k_ln_scan<<<MPAD + 1, 256, 0, stream>>>(hpre, ftb, lng, lnb, h0big, cnt, off);
    // 4. GEMM1 (K'=1024) + fused att-dots + CSR scatter
    k_tgemm<16, true, 2><<<GEMM_BLKS + 313, 512, 0, stream>>>(
        h0big, B1, nullptr, h1b, as1, ad1, aS1, aD1,
        ei, nullptr, off, cursor, csrc);
    // 5. layer-1 aggregation, head-sliced (fused bias+BN+ReLU -> bf16 h2)
    k_agg1slice<<<(N_NODES / 8) * 8, 256, 0, stream>>>(
        csrc, off, h1b, aS1, aD1, b1, bnm, bnv, bng, bnb, h2b);
    // 6. GEMM2 + fused att2
    k_gemm2att<<<N_NODES / 16, 256, 0, stream>>>(h2b, W2, as2, ad2, gbuf, aS2, aD2);
    // 7. layer-2 aggregation (fused head-mean + b2)
    k_agg2csr<<<(N_NODES + 3) / 4, 256, 0, stream>>>(csrc, off, gbuf, aS2, aD2, b2, out);
}

// Round 14
// 123.085 us; speedup vs baseline: 1.2853x; 1.2853x over previous
//
#include <hip/hip_runtime.h>
#include <hip/hip_bf16.h>
#include <math.h>

#define N_NODES 10000
#define N_EDGES 160000
#define DIN 128
#define DW 512
#define NHEAD 8
#define NC 64
#define MPAD 10112     // 79 * 128
#define GEMM_BLKS 316  // 79 * 4

typedef unsigned short ushort_t;
typedef __attribute__((ext_vector_type(8))) short bf16x8;
typedef __attribute__((ext_vector_type(8))) unsigned short us8;
typedef __attribute__((ext_vector_type(4))) float f32x4;
typedef __attribute__((ext_vector_type(4))) unsigned int u32x4;

__device__ inline ushort_t f2bf(float v) {
    unsigned u = __builtin_bit_cast(unsigned, v);
    return (ushort_t)((u + 0x7fff + ((u >> 16) & 1)) >> 16);
}
__device__ inline float bf2f(ushort_t h) {
    return __builtin_bit_cast(float, (unsigned)h << 16);
}

// swizzled tile-major index: tiles of 128 rows x 64 k, 8192 ushort each.
__device__ __forceinline__ size_t swz_idx(int rb, int r, int kp, int nkt) {
    int kt = kp >> 6, kc = kp & 63;
    return ((size_t)(rb * nkt + kt)) * 8192 + r * 64 + (kc ^ ((r & 7) << 3));
}

__device__ __forceinline__ void gld16(const ushort_t* g, ushort_t* l) {
    __builtin_amdgcn_global_load_lds(
        (const __attribute__((address_space(1))) void*)g,
        (__attribute__((address_space(3))) void*)l, 16, 0, 0);
}

// ================= merged prep: prepx(vec) + prepWft + prepW1 + zero =================
__global__ void k_prep(const float* __restrict__ x, const float* __restrict__ ftW,
                       const float* __restrict__ W1f,
                       ushort_t* __restrict__ Ax, ushort_t* __restrict__ Bx,
                       ushort_t* __restrict__ B1,
                       int* __restrict__ cnt, int* __restrict__ cursor) {
    int bid = blockIdx.x, t = threadIdx.x;
    if (bid < 632) {                        // prepx: Ax[MPAD][256] = [xhi | xlo], 16B stores
        int gid = bid * 256 + t;            // n * 16 + chunk
        int n = gid >> 4, k0 = (gid & 15) * 8;
        float v[8];
        if (n < N_NODES) {
            #pragma unroll
            for (int u = 0; u < 8; u++) v[u] = x[n * DIN + k0 + u];
        } else {
            #pragma unroll
            for (int u = 0; u < 8; u++) v[u] = 0.f;
        }
        us8 hi, lo;
        #pragma unroll
        for (int u = 0; u < 8; u++) {
            ushort_t h = f2bf(v[u]);
            hi[u] = h;
            lo[u] = f2bf(v[u] - bf2f(h));
        }
        int rb = n >> 7, r = n & 127;
        *(us8*)(Ax + swz_idx(rb, r, k0, 4)) = hi;
        *(us8*)(Ax + swz_idx(rb, r, 128 + k0, 4)) = lo;
    } else if (bid < 888) {                 // prepWft: Bx[512][256] = [Whi | Whi]
        int i = (bid - 632) * 256 + t;
        int n = i >> 7, k = i & 127;
        ushort_t h = f2bf(ftW[k * DW + n]);
        int cb = n >> 7, rc = n & 127;
        Bx[swz_idx(cb, rc, k, 4)] = h;
        Bx[swz_idx(cb, rc, 128 + k, 4)] = h;
    } else if (bid < 1912) {                // prepW1: B1[512][1024] = [W1hi | W1hi]
        int i = (bid - 888) * 256 + t;
        int n = i >> 9, k = i & 511;
        ushort_t h = f2bf(W1f[k * DW + n]);
        int cb = n >> 7, rc = n & 127;
        B1[swz_idx(cb, rc, k, 16)] = h;
        B1[swz_idx(cb, rc, 512 + k, 16)] = h;
    } else {                                // zero cnt/cursor
        int i = (bid - 1912) * 256 + t;
        if (i < N_NODES) { cnt[i] = 0; cursor[i] = 0; }
    }
}

// ================= LDS-DMA double-buffered bf16 MFMA GEMM, 8 waves (+side work) =================
template<int KT, bool ATT, int EXTRA>
__global__ __launch_bounds__(512, 4) void k_tgemm(const ushort_t* __restrict__ A,
                                                  const ushort_t* __restrict__ Bm,
                                                  float* __restrict__ C,
                                                  ushort_t* __restrict__ Cb,
                                                  const float* __restrict__ asrc,
                                                  const float* __restrict__ adst,
                                                  float* __restrict__ aS,
                                                  float* __restrict__ aD,
                                                  const int* __restrict__ ei,
                                                  int* __restrict__ cnt,
                                                  const int* __restrict__ off,
                                                  int* __restrict__ cursor,
                                                  int* __restrict__ csrc) {
    __shared__ __align__(16) ushort_t As[2][8192];
    __shared__ __align__(16) ushort_t Bs[2][8192];
    int bid = blockIdx.x;
    if (bid >= GEMM_BLKS) {                 // ---- CSR side work ----
        int e = (bid - GEMM_BLKS) * 512 + threadIdx.x;
        if (e < N_EDGES) {
            if (EXTRA == 1) {
                atomicAdd(&cnt[ei[N_EDGES + e]], 1);
            } else {
                int d = ei[N_EDGES + e];
                int p = off[d] + atomicAdd(&cursor[d], 1);
                csrc[p] = ei[e];
            }
        }
        return;
    }
    int bx = bid >> 2, by = bid & 3;
    int t = threadIdx.x, w = t >> 6, l = t & 63;
    int lm = l & 15, g = l >> 4;
    int wr = w >> 1, wc = w & 1;            // 4 row-stripes x 2 col-stripes
    int rowbase = bx * 128;
    int colbase = by * 128;

    const ushort_t* Abase = A + (size_t)bx * KT * 8192 + t * 8;
    const ushort_t* Bbase = Bm + (size_t)by * KT * 8192 + t * 8;

    f32x4 acc[2][4];
    #pragma unroll
    for (int r = 0; r < 2; r++)
        #pragma unroll
        for (int c = 0; c < 4; c++) acc[r][c] = (f32x4){0.f, 0.f, 0.f, 0.f};

    {   // prologue: tile 0 -> buf 0 (4 DMA/thread)
        #pragma unroll
        for (int j = 0; j < 2; ++j) {
            gld16(Abase + j * 4096, &As[0][j * 4096 + t * 8]);
            gld16(Bbase + j * 4096, &Bs[0][j * 4096 + t * 8]);
        }
    }

    int p = 0;
    for (int kt = 0; kt < KT; ++kt) {
        __builtin_amdgcn_s_barrier();       // all waves done reading buf[p^1]
        if (kt + 1 < KT) {
            const ushort_t* ga = Abase + (size_t)(kt + 1) * 8192;
            const ushort_t* gb = Bbase + (size_t)(kt + 1) * 8192;
            #pragma unroll
            for (int j = 0; j < 2; ++j) {
                gld16(ga + j * 4096, &As[p ^ 1][j * 4096 + t * 8]);
                gld16(gb + j * 4096, &Bs[p ^ 1][j * 4096 + t * 8]);
            }
            asm volatile("s_waitcnt vmcnt(4)" ::: "memory");   // tile kt landed
        } else {
            asm volatile("s_waitcnt vmcnt(0)" ::: "memory");
        }
        __builtin_amdgcn_s_barrier();       // ALL waves' tile-kt DMA complete
        const char* Ap = (const char*)As[p];
        const char* Bp = (const char*)Bs[p];
        #pragma unroll
        for (int ks = 0; ks < 2; ++ks) {
            bf16x8 af[2], bfr[4];
            #pragma unroll
            for (int r = 0; r < 2; ++r) {
                int row = wr * 32 + r * 16 + lm;
                af[r] = *(const bf16x8*)(Ap + row * 128 +
                                         ((ks * 64 + g * 16) ^ ((row & 7) << 4)));
            }
            #pragma unroll
            for (int c = 0; c < 4; ++c) {
                int col = wc * 64 + c * 16 + lm;
                bfr[c] = *(const bf16x8*)(Bp + col * 128 +
                                          ((ks * 64 + g * 16) ^ ((col & 7) << 4)));
            }
            #pragma unroll
            for (int r = 0; r < 2; ++r)
                #pragma unroll
                for (int c = 0; c < 4; ++c)
                    acc[r][c] = __builtin_amdgcn_mfma_f32_16x16x32_bf16(af[r], bfr[c], acc[r][c], 0, 0, 0);
        }
        p ^= 1;
    }

    // C/D map: col = lane&15, row = (lane>>4)*4 + q
    if (!ATT) {
        #pragma unroll
        for (int r = 0; r < 2; ++r) {
            int row0 = rowbase + wr * 32 + r * 16 + g * 4;
            #pragma unroll
            for (int c = 0; c < 4; ++c) {
                int col = colbase + wc * 64 + c * 16 + lm;
                #pragma unroll
                for (int q = 0; q < 4; ++q)
                    if (row0 + q < N_NODES) C[(size_t)(row0 + q) * DW + col] = acc[r][c][q];
            }
        }
    } else {
        int h = 2 * by + wc;                  // this wave's head
        float asv[4], adv[4];
        #pragma unroll
        for (int c = 0; c < 4; ++c) {
            asv[c] = asrc[h * NC + c * 16 + lm];
            adv[c] = adst[h * NC + c * 16 + lm];
        }
        #pragma unroll
        for (int r = 0; r < 2; ++r) {
            int row0 = rowbase + wr * 32 + r * 16 + g * 4;
            #pragma unroll
            for (int c = 0; c < 4; ++c) {
                int col = colbase + wc * 64 + c * 16 + lm;
                #pragma unroll
                for (int q = 0; q < 4; ++q)
                    if (row0 + q < N_NODES) Cb[(size_t)(row0 + q) * DW + col] = f2bf(acc[r][c][q]);
            }
            #pragma unroll
            for (int q = 0; q < 4; ++q) {
                float ss = acc[r][0][q] * asv[0] + acc[r][1][q] * asv[1] +
                           acc[r][2][q] * asv[2] + acc[r][3][q] * asv[3];
                float dd = acc[r][0][q] * adv[0] + acc[r][1][q] * adv[1] +
                           acc[r][2][q] * adv[2] + acc[r][3][q] * adv[3];
                #pragma unroll
                for (int m = 1; m < 16; m <<= 1) {
                    ss += __shfl_xor(ss, m, 64);
                    dd += __shfl_xor(dd, m, 64);
                }
                int row = row0 + q;
                if (lm == 0 && row < N_NODES) {
                    aS[row * NHEAD + h] = ss;
                    aD[row * NHEAD + h] = dd;
                }
            }
        }
    }
}

// ================= LN epilogue -> h0big[*][1024] = [hi | lo], vectorized (+ scan block) =================
__global__ __launch_bounds__(256) void k_ln_scan(const float* __restrict__ hpre,
                                                 const float* __restrict__ fb,
                                                 const float* __restrict__ g,
                                                 const float* __restrict__ beta,
                                                 ushort_t* __restrict__ h0big,
                                                 const int* __restrict__ cnt,
                                                 int* __restrict__ off) {
    __shared__ int ps[256];
    __shared__ float red[8];
    __shared__ __align__(16) ushort_t st[1024];
    int bid = blockIdx.x, t = threadIdx.x;
    if (bid == MPAD) {                       // ---- exclusive scan over cnt ----
        int base = t * 40;
        int loc[40];
        int s = 0;
        #pragma unroll
        for (int i = 0; i < 40; i++) {
            int idx = base + i;
            int v = idx < N_NODES ? cnt[idx] : 0;
            loc[i] = s; s += v;
        }
        ps[t] = s; __syncthreads();
        for (int o = 1; o < 256; o <<= 1) {
            int v = (t >= o) ? ps[t - o] : 0;
            __syncthreads();
            ps[t] += v;
            __syncthreads();
        }
        int pre = (t > 0) ? ps[t - 1] : 0;
        #pragma unroll
        for (int i = 0; i < 40; i++) {
            int idx = base + i;
            if (idx < N_NODES) off[idx] = pre + loc[i];
        }
        if (t == 255) off[N_NODES] = ps[255];
        return;
    }
    int n = bid;
    int rb = n >> 7, r = n & 127;
    if (n >= N_NODES) {
        if (t < 128) {
            int kp0 = t * 8;
            *(us8*)(h0big + swz_idx(rb, r, kp0, 16)) = (us8){0,0,0,0,0,0,0,0};
        }
        return;
    }
    float a0 = hpre[(size_t)n * DW + t] + fb[t];
    float a1 = hpre[(size_t)n * DW + t + 256] + fb[t + 256];
    float s = a0 + a1, sq = a0 * a0 + a1 * a1;
    for (int o = 32; o > 0; o >>= 1) { s += __shfl_down(s, o, 64); sq += __shfl_down(sq, o, 64); }
    int wid = t >> 6;
    if ((t & 63) == 0) { red[wid] = s; red[4 + wid] = sq; }
    __syncthreads();
    if (t == 0) {
        float ts = red[0] + red[1] + red[2] + red[3];
        float tq = red[4] + red[5] + red[6] + red[7];
        float mu = ts / DW;
        float var = tq / DW - mu * mu;
        red[0] = mu; red[1] = rsqrtf(var + 1e-5f);
    }
    __syncthreads();
    float mu = red[0], rs = red[1];
    float v0 = (a0 - mu) * rs * g[t] + beta[t];
    float v1 = (a1 - mu) * rs * g[t + 256] + beta[t + 256];
    v0 = v0 >= 0.f ? v0 : 0.2f * v0;
    v1 = v1 >= 0.f ? v1 : 0.2f * v1;
    ushort_t h0_ = f2bf(v0), l0_ = f2bf(v0 - bf2f(h0_));
    ushort_t h1_ = f2bf(v1), l1_ = f2bf(v1 - bf2f(h1_));
    st[t] = h0_;        st[256 + t] = h1_;      // hi occupies kp 0..511
    st[512 + t] = l0_;  st[768 + t] = l1_;      // lo occupies kp 512..1023
    __syncthreads();
    if (t < 128) {
        int kp0 = t * 8;
        *(us8*)(h0big + swz_idx(rb, r, kp0, 16)) = *(const us8*)(st + kp0);
    }
}

// ================= layer-1 aggregation: WAVE per node, no syncs, no LDS =================
// Lane owns 8 contiguous cols (16B gather loads). Per-lane exp over ALL edges of the
// node => den is already the COMPLETE denominator for this head (no cross-lane
// reduce! round-13 bug: reducing 8 identical complete sums gave 8x denominator).
__global__ __launch_bounds__(256) void k_agg1wave(
    const int* __restrict__ csrc, const int* __restrict__ off,
    const ushort_t* __restrict__ h1b,
    const float* __restrict__ aS, const float* __restrict__ aD,
    const float* __restrict__ b1, const float* __restrict__ bnm,
    const float* __restrict__ bnv, const float* __restrict__ bng,
    const float* __restrict__ bnb, ushort_t* __restrict__ h2b)
{
    int t = threadIdx.x;
    int n = blockIdx.x * 4 + (t >> 6);
    int lane = t & 63;
    if (n >= N_NODES) return;
    int j0 = lane * 8;                     // this lane's 8 columns
    int hA = lane >> 3;                    // head of those columns
    float adn = aD[n * NHEAD + hA];
    int beg = off[n], end = off[n + 1];
    float acc[8];
    #pragma unroll
    for (int q = 0; q < 8; q++) acc[q] = 0.f;
    float den = 0.f;
    int c = beg;
    for (; c + 2 <= end; c += 2) {         // 2 edges in flight
        int s0 = csrc[c], s1 = csrc[c + 1];
        float l0 = aS[s0 * NHEAD + hA] + adn;
        float l1 = aS[s1 * NHEAD + hA] + adn;
        us8 v0 = *(const us8*)(h1b + (size_t)s0 * DW + j0);
        us8 v1 = *(const us8*)(h1b + (size_t)s1 * DW + j0);
        l0 = l0 >= 0.f ? l0 : 0.2f * l0;
        l1 = l1 >= 0.f ? l1 : 0.2f * l1;
        float w0 = __expf(l0), w1 = __expf(l1);
        den += w0 + w1;
        #pragma unroll
        for (int q = 0; q < 8; q++) {
            acc[q] += w0 * bf2f(v0[q]);
            acc[q] += w1 * bf2f(v1[q]);
        }
    }
    if (c < end) {
        int s0 = csrc[c];
        float l0 = aS[s0 * NHEAD + hA] + adn;
        us8 v0 = *(const us8*)(h1b + (size_t)s0 * DW + j0);
        l0 = l0 >= 0.f ? l0 : 0.2f * l0;
        float w0 = __expf(l0);
        den += w0;
        #pragma unroll
        for (int q = 0; q < 8; q++) acc[q] += w0 * bf2f(v0[q]);
    }
    // den is already complete for this (n, head) — NO cross-lane reduce.
    float rd = den > 0.f ? 1.f / den : 0.f;
    unsigned pk[4];
    #pragma unroll
    for (int q = 0; q < 4; q++) {
        int ja = j0 + 2 * q, jb = ja + 1;
        float va = (acc[2 * q] * rd + b1[ja] - bnm[ja]) * (rsqrtf(bnv[ja] + 1e-5f) * bng[ja]) + bnb[ja];
        float vb = (acc[2 * q + 1] * rd + b1[jb] - bnm[jb]) * (rsqrtf(bnv[jb] + 1e-5f) * bng[jb]) + bnb[jb];
        va = va > 0.f ? va : 0.f;
        vb = vb > 0.f ? vb : 0.f;
        pk[q] = (unsigned)f2bf(va) | ((unsigned)f2bf(vb) << 16);
    }
    *(u32x4*)(h2b + (size_t)n * DW + j0) = (u32x4){pk[0], pk[1], pk[2], pk[3]};
}

// ================= GEMM2 + fused att2 (from h2 bf16) =================
__global__ __launch_bounds__(256) void k_gemm2att(const ushort_t* __restrict__ h2b,
                                                  const float* __restrict__ W2,
                                                  const float* __restrict__ as2,
                                                  const float* __restrict__ ad2,
                                                  float* __restrict__ gout,
                                                  float* __restrict__ aS,
                                                  float* __restrict__ aD) {
    __shared__ float Ws[DW * 16];
    __shared__ float gl[16][16];
    __shared__ float a2[32];
    int t = threadIdx.x;
    for (int i = t; i < DW * 16; i += 256) Ws[i] = W2[i];
    if (t < 16) a2[t] = as2[t];
    else if (t < 32) a2[t] = ad2[t - 16];
    __syncthreads();
    int nb = blockIdx.x * 16;
    int nl = t >> 4, j = t & 15;
    const bf16x8* hr = (const bf16x8*)(h2b + (size_t)(nb + nl) * DW);
    float acc = 0.f;
    for (int ks = 0; ks < DW / 8; ks++) {
        bf16x8 v = hr[ks];
        #pragma unroll
        for (int u = 0; u < 8; u++)
            acc += bf2f((ushort_t)v[u]) * Ws[(ks * 8 + u) * 16 + j];
    }
    gout[(nb + nl) * 16 + j] = acc;
    gl[nl][j] = acc;
    __syncthreads();
    if (j < 8) {
        aS[(nb + nl) * NHEAD + j] = gl[nl][2 * j] * a2[2 * j] + gl[nl][2 * j + 1] * a2[2 * j + 1];
    } else {
        int h = j - 8;
        aD[(nb + nl) * NHEAD + h] = gl[nl][2 * h] * a2[16 + 2 * h] + gl[nl][2 * h + 1] * a2[16 + 2 * h + 1];
    }
}

// ================= layer-2 aggregation, CSR, fused head-mean + b2 =================
__global__ __launch_bounds__(256) void k_agg2csr(
    const int* __restrict__ csrc, const int* __restrict__ off,
    const float* __restrict__ gbuf,
    const float* __restrict__ aS, const float* __restrict__ aD,
    const float* __restrict__ b2, float* __restrict__ outp)
{
    int t = threadIdx.x;
    int n = blockIdx.x * 4 + (t >> 6);
    int lane = t & 63;
    if (n >= N_NODES) return;
    int beg = off[n], end = off[n + 1];
    int j = lane & 15, slot = lane >> 4, h = j >> 1;
    float adn = aD[n * NHEAD + h];
    float acc = 0.f, den = 0.f;
    for (int c = beg + slot; c < end; c += 4) {
        int s = csrc[c];
        float l = aS[s * NHEAD + h] + adn;
        l = l >= 0.f ? l : 0.2f * l;
        float w = __expf(l);
        den += w;
        acc += w * gbuf[s * 16 + j];
    }
    acc += __shfl_down(acc, 16, 64); acc += __shfl_down(acc, 32, 64);
    den += __shfl_down(den, 16, 64); den += __shfl_down(den, 32, 64);
    float v = (lane < 16 && den > 0.f) ? acc / den : 0.f;
    v += __shfl_down(v, 2, 64);
    v += __shfl_down(v, 4, 64);
    v += __shfl_down(v, 8, 64);
    if (lane < 2) outp[n * 2 + lane] = v * 0.125f + b2[lane];
}

extern "C" void kernel_launch(void* const* d_in, const int* in_sizes, int n_in,
                              void* d_out, int out_size, void* d_ws, size_t ws_size,
                              hipStream_t stream) {
    const float* x    = (const float*)d_in[0];
    const int*   ei   = (const int*)d_in[1];
    const float* ftW  = (const float*)d_in[2];
    const float* ftb  = (const float*)d_in[3];
    const float* lng  = (const float*)d_in[4];
    const float* lnb  = (const float*)d_in[5];
    const float* W1   = (const float*)d_in[6];
    const float* as1  = (const float*)d_in[7];
    const float* ad1  = (const float*)d_in[8];
    const float* b1   = (const float*)d_in[9];
    const float* bng  = (const float*)d_in[10];
    const float* bnb  = (const float*)d_in[11];
    const float* bnm  = (const float*)d_in[12];
    const float* bnv  = (const float*)d_in[13];
    const float* W2   = (const float*)d_in[14];
    const float* as2  = (const float*)d_in[15];
    const float* ad2  = (const float*)d_in[16];
    const float* b2   = (const float*)d_in[17];
    float* out = (float*)d_out;

    // ---- workspace (float offsets), lifetime-aliased, ~60.2 MB ----
    float* F = (float*)d_ws;
    ushort_t* Ax    = (ushort_t*)(F + 0);          // dead after ft GEMM
    float*    gbuf  = F + 0;                       // 160,000 f
    ushort_t* Bx    = (ushort_t*)(F + 1294336);
    ushort_t* B1    = (ushort_t*)(F + 1359872);
    float*    hpre  = F + 1622016;                 // dead after LN
    ushort_t* h2b   = (ushort_t*)(F + 1622016);    // written by agg1wave
    ushort_t* h0big = (ushort_t*)(F + 6799360);
    ushort_t* h1b   = (ushort_t*)(F + 11976704);
    float*    aS1   = F + 14536704;
    float*    aD1   = F + 14616704;
    float*    aS2   = F + 14696704;
    float*    aD2   = F + 14776704;
    int* cnt        = (int*)(F + 14856704);
    int* cursor     = (int*)(F + 14866704);
    int* off        = (int*)(F + 14876704);
    int* csrc       = (int*)(F + 14886705);

    // 1. merged prep (Ax-vec + Bx + B1 + zero)
    k_prep<<<1952, 256, 0, stream>>>(x, ftW, W1, Ax, Bx, B1, cnt, cursor);
    // 2. ft GEMM (K'=256) + CSR count
    k_tgemm<4, false, 1><<<GEMM_BLKS + 313, 512, 0, stream>>>(
        Ax, Bx, hpre, nullptr, nullptr, nullptr, nullptr, nullptr,
        ei, cnt, nullptr, nullptr, nullptr);
    // 3. LN -> h0big (K'=1024 [hi|lo], vectorized) + CSR scan
    k_ln_scan<<<MPAD + 1, 256, 0, stream>>>(hpre, ftb, lng, lnb, h0big, cnt, off);
    // 4. GEMM1 (K'=1024) + fused att-dots + CSR scatter
    k_tgemm<16, true, 2><<<GEMM_BLKS + 313, 512, 0, stream>>>(
        h0big, B1, nullptr, h1b, as1, ad1, aS1, aD1,
        ei, nullptr, off, cursor, csrc);
    // 5. layer-1 aggregation: wave per node, no syncs (fused bias+BN+ReLU -> bf16 h2)
    k_agg1wave<<<(N_NODES + 3) / 4, 256, 0, stream>>>(
        csrc, off, h1b, aS1, aD1, b1, bnm, bnv, bng, bnb, h2b);
    // 6. GEMM2 + fused att2
    k_gemm2att<<<N_NODES / 16, 256, 0, stream>>>(h2b, W2, as2, ad2, gbuf, aS2, aD2);
    // 7. layer-2 aggregation (fused head-mean + b2)
    k_agg2csr<<<(N_NODES + 3) / 4, 256, 0, stream>>>(csrc, off, gbuf, aS2, aD2, b2, out);
}

// Round 15
// 120.735 us; speedup vs baseline: 1.3103x; 1.0195x over previous
//
#include <hip/hip_runtime.h>
#include <hip/hip_bf16.h>
#include <math.h>

#define N_NODES 10000
#define N_EDGES 160000
#define DIN 128
#define DW 512
#define NHEAD 8
#define NC 64
#define MPAD 10112     // 79 * 128
#define GEMM_BLKS 316  // 79 * 4

typedef unsigned short ushort_t;
typedef __attribute__((ext_vector_type(8))) short bf16x8;
typedef __attribute__((ext_vector_type(8))) unsigned short us8;
typedef __attribute__((ext_vector_type(4))) float f32x4;
typedef __attribute__((ext_vector_type(4))) unsigned int u32x4;

__device__ inline ushort_t f2bf(float v) {
    unsigned u = __builtin_bit_cast(unsigned, v);
    return (ushort_t)((u + 0x7fff + ((u >> 16) & 1)) >> 16);
}
__device__ inline float bf2f(ushort_t h) {
    return __builtin_bit_cast(float, (unsigned)h << 16);
}

// swizzled tile-major index: tiles of 128 rows x 64 k, 8192 ushort each.
__device__ __forceinline__ size_t swz_idx(int rb, int r, int kp, int nkt) {
    int kt = kp >> 6, kc = kp & 63;
    return ((size_t)(rb * nkt + kt)) * 8192 + r * 64 + (kc ^ ((r & 7) << 3));
}

__device__ __forceinline__ void gld16(const ushort_t* g, ushort_t* l) {
    __builtin_amdgcn_global_load_lds(
        (const __attribute__((address_space(1))) void*)g,
        (__attribute__((address_space(3))) void*)l, 16, 0, 0);
}

// ================= merged prep: prepx(vec) + prepWft + prepW1 + zero =================
__global__ void k_prep(const float* __restrict__ x, const float* __restrict__ ftW,
                       const float* __restrict__ W1f,
                       ushort_t* __restrict__ Ax, ushort_t* __restrict__ Bx,
                       ushort_t* __restrict__ B1,
                       int* __restrict__ cnt, int* __restrict__ cursor) {
    int bid = blockIdx.x, t = threadIdx.x;
    if (bid < 632) {                        // prepx: Ax[MPAD][256] = [xhi | xlo], 16B stores
        int gid = bid * 256 + t;            // n * 16 + chunk
        int n = gid >> 4, k0 = (gid & 15) * 8;
        float v[8];
        if (n < N_NODES) {
            #pragma unroll
            for (int u = 0; u < 8; u++) v[u] = x[n * DIN + k0 + u];
        } else {
            #pragma unroll
            for (int u = 0; u < 8; u++) v[u] = 0.f;
        }
        us8 hi, lo;
        #pragma unroll
        for (int u = 0; u < 8; u++) {
            ushort_t h = f2bf(v[u]);
            hi[u] = h;
            lo[u] = f2bf(v[u] - bf2f(h));
        }
        int rb = n >> 7, r = n & 127;
        *(us8*)(Ax + swz_idx(rb, r, k0, 4)) = hi;
        *(us8*)(Ax + swz_idx(rb, r, 128 + k0, 4)) = lo;
    } else if (bid < 888) {                 // prepWft: Bx[512][256] = [Whi | Whi]
        int i = (bid - 632) * 256 + t;
        int n = i >> 7, k = i & 127;
        ushort_t h = f2bf(ftW[k * DW + n]);
        int cb = n >> 7, rc = n & 127;
        Bx[swz_idx(cb, rc, k, 4)] = h;
        Bx[swz_idx(cb, rc, 128 + k, 4)] = h;
    } else if (bid < 1912) {                // prepW1: B1[512][1024] = [W1hi | W1hi]
        int i = (bid - 888) * 256 + t;
        int n = i >> 9, k = i & 511;
        ushort_t h = f2bf(W1f[k * DW + n]);
        int cb = n >> 7, rc = n & 127;
        B1[swz_idx(cb, rc, k, 16)] = h;
        B1[swz_idx(cb, rc, 512 + k, 16)] = h;
    } else {                                // zero cnt/cursor
        int i = (bid - 1912) * 256 + t;
        if (i < N_NODES) { cnt[i] = 0; cursor[i] = 0; }
    }
}

// ================= LDS-DMA double-buffered bf16 MFMA GEMM, 8 waves (+side work) =================
template<int KT, bool ATT, int EXTRA>
__global__ __launch_bounds__(512, 4) void k_tgemm(const ushort_t* __restrict__ A,
                                                  const ushort_t* __restrict__ Bm,
                                                  float* __restrict__ C,
                                                  ushort_t* __restrict__ Cb,
                                                  const float* __restrict__ asrc,
                                                  const float* __restrict__ adst,
                                                  float* __restrict__ aS,
                                                  float* __restrict__ aD,
                                                  const int* __restrict__ ei,
                                                  int* __restrict__ cnt,
                                                  const int* __restrict__ off,
                                                  int* __restrict__ cursor,
                                                  int* __restrict__ csrc) {
    __shared__ __align__(16) ushort_t As[2][8192];
    __shared__ __align__(16) ushort_t Bs[2][8192];
    int bid = blockIdx.x;
    if (bid >= GEMM_BLKS) {                 // ---- CSR side work ----
        int e = (bid - GEMM_BLKS) * 512 + threadIdx.x;
        if (e < N_EDGES) {
            if (EXTRA == 1) {
                atomicAdd(&cnt[ei[N_EDGES + e]], 1);
            } else {
                int d = ei[N_EDGES + e];
                int p = off[d] + atomicAdd(&cursor[d], 1);
                csrc[p] = ei[e];
            }
        }
        return;
    }
    int bx = bid >> 2, by = bid & 3;
    int t = threadIdx.x, w = t >> 6, l = t & 63;
    int lm = l & 15, g = l >> 4;
    int wr = w >> 1, wc = w & 1;            // 4 row-stripes x 2 col-stripes
    int rowbase = bx * 128;
    int colbase = by * 128;

    const ushort_t* Abase = A + (size_t)bx * KT * 8192 + t * 8;
    const ushort_t* Bbase = Bm + (size_t)by * KT * 8192 + t * 8;

    f32x4 acc[2][4];
    #pragma unroll
    for (int r = 0; r < 2; r++)
        #pragma unroll
        for (int c = 0; c < 4; c++) acc[r][c] = (f32x4){0.f, 0.f, 0.f, 0.f};

    {   // prologue: tile 0 -> buf 0 (4 DMA/thread)
        #pragma unroll
        for (int j = 0; j < 2; ++j) {
            gld16(Abase + j * 4096, &As[0][j * 4096 + t * 8]);
            gld16(Bbase + j * 4096, &Bs[0][j * 4096 + t * 8]);
        }
    }

    int p = 0;
    for (int kt = 0; kt < KT; ++kt) {
        __builtin_amdgcn_s_barrier();       // all waves done reading buf[p^1]
        if (kt + 1 < KT) {
            const ushort_t* ga = Abase + (size_t)(kt + 1) * 8192;
            const ushort_t* gb = Bbase + (size_t)(kt + 1) * 8192;
            #pragma unroll
            for (int j = 0; j < 2; ++j) {
                gld16(ga + j * 4096, &As[p ^ 1][j * 4096 + t * 8]);
                gld16(gb + j * 4096, &Bs[p ^ 1][j * 4096 + t * 8]);
            }
            asm volatile("s_waitcnt vmcnt(4)" ::: "memory");   // tile kt landed
        } else {
            asm volatile("s_waitcnt vmcnt(0)" ::: "memory");
        }
        __builtin_amdgcn_s_barrier();       // ALL waves' tile-kt DMA complete
        const char* Ap = (const char*)As[p];
        const char* Bp = (const char*)Bs[p];
        #pragma unroll
        for (int ks = 0; ks < 2; ++ks) {
            bf16x8 af[2], bfr[4];
            #pragma unroll
            for (int r = 0; r < 2; ++r) {
                int row = wr * 32 + r * 16 + lm;
                af[r] = *(const bf16x8*)(Ap + row * 128 +
                                         ((ks * 64 + g * 16) ^ ((row & 7) << 4)));
            }
            #pragma unroll
            for (int c = 0; c < 4; ++c) {
                int col = wc * 64 + c * 16 + lm;
                bfr[c] = *(const bf16x8*)(Bp + col * 128 +
                                          ((ks * 64 + g * 16) ^ ((col & 7) << 4)));
            }
            #pragma unroll
            for (int r = 0; r < 2; ++r)
                #pragma unroll
                for (int c = 0; c < 4; ++c)
                    acc[r][c] = __builtin_amdgcn_mfma_f32_16x16x32_bf16(af[r], bfr[c], acc[r][c], 0, 0, 0);
        }
        p ^= 1;
    }

    // C/D map: col = lane&15, row = (lane>>4)*4 + q
    if (!ATT) {
        #pragma unroll
        for (int r = 0; r < 2; ++r) {
            int row0 = rowbase + wr * 32 + r * 16 + g * 4;
            #pragma unroll
            for (int c = 0; c < 4; ++c) {
                int col = colbase + wc * 64 + c * 16 + lm;
                #pragma unroll
                for (int q = 0; q < 4; ++q)
                    if (row0 + q < N_NODES) C[(size_t)(row0 + q) * DW + col] = acc[r][c][q];
            }
        }
    } else {
        int h = 2 * by + wc;                  // this wave's head
        float asv[4], adv[4];
        #pragma unroll
        for (int c = 0; c < 4; ++c) {
            asv[c] = asrc[h * NC + c * 16 + lm];
            adv[c] = adst[h * NC + c * 16 + lm];
        }
        #pragma unroll
        for (int r = 0; r < 2; ++r) {
            int row0 = rowbase + wr * 32 + r * 16 + g * 4;
            #pragma unroll
            for (int c = 0; c < 4; ++c) {
                int col = colbase + wc * 64 + c * 16 + lm;
                #pragma unroll
                for (int q = 0; q < 4; ++q)
                    if (row0 + q < N_NODES) Cb[(size_t)(row0 + q) * DW + col] = f2bf(acc[r][c][q]);
            }
            #pragma unroll
            for (int q = 0; q < 4; ++q) {
                float ss = acc[r][0][q] * asv[0] + acc[r][1][q] * asv[1] +
                           acc[r][2][q] * asv[2] + acc[r][3][q] * asv[3];
                float dd = acc[r][0][q] * adv[0] + acc[r][1][q] * adv[1] +
                           acc[r][2][q] * adv[2] + acc[r][3][q] * adv[3];
                #pragma unroll
                for (int m = 1; m < 16; m <<= 1) {
                    ss += __shfl_xor(ss, m, 64);
                    dd += __shfl_xor(dd, m, 64);
                }
                int row = row0 + q;
                if (lm == 0 && row < N_NODES) {
                    aS[row * NHEAD + h] = ss;
                    aD[row * NHEAD + h] = dd;
                }
            }
        }
    }
}

// ================= LN epilogue -> h0big[*][1024] = [hi | lo], vectorized (+ scan block) =================
__global__ __launch_bounds__(256) void k_ln_scan(const float* __restrict__ hpre,
                                                 const float* __restrict__ fb,
                                                 const float* __restrict__ g,
                                                 const float* __restrict__ beta,
                                                 ushort_t* __restrict__ h0big,
                                                 const int* __restrict__ cnt,
                                                 int* __restrict__ off) {
    __shared__ int ps[256];
    __shared__ float red[8];
    __shared__ __align__(16) ushort_t st[1024];
    int bid = blockIdx.x, t = threadIdx.x;
    if (bid == MPAD) {                       // ---- exclusive scan over cnt ----
        int base = t * 40;
        int loc[40];
        int s = 0;
        #pragma unroll
        for (int i = 0; i < 40; i++) {
            int idx = base + i;
            int v = idx < N_NODES ? cnt[idx] : 0;
            loc[i] = s; s += v;
        }
        ps[t] = s; __syncthreads();
        for (int o = 1; o < 256; o <<= 1) {
            int v = (t >= o) ? ps[t - o] : 0;
            __syncthreads();
            ps[t] += v;
            __syncthreads();
        }
        int pre = (t > 0) ? ps[t - 1] : 0;
        #pragma unroll
        for (int i = 0; i < 40; i++) {
            int idx = base + i;
            if (idx < N_NODES) off[idx] = pre + loc[i];
        }
        if (t == 255) off[N_NODES] = ps[255];
        return;
    }
    int n = bid;
    int rb = n >> 7, r = n & 127;
    if (n >= N_NODES) {
        if (t < 128) {
            int kp0 = t * 8;
            *(us8*)(h0big + swz_idx(rb, r, kp0, 16)) = (us8){0,0,0,0,0,0,0,0};
        }
        return;
    }
    float a0 = hpre[(size_t)n * DW + t] + fb[t];
    float a1 = hpre[(size_t)n * DW + t + 256] + fb[t + 256];
    float s = a0 + a1, sq = a0 * a0 + a1 * a1;
    for (int o = 32; o > 0; o >>= 1) { s += __shfl_down(s, o, 64); sq += __shfl_down(sq, o, 64); }
    int wid = t >> 6;
    if ((t & 63) == 0) { red[wid] = s; red[4 + wid] = sq; }
    __syncthreads();
    if (t == 0) {
        float ts = red[0] + red[1] + red[2] + red[3];
        float tq = red[4] + red[5] + red[6] + red[7];
        float mu = ts / DW;
        float var = tq / DW - mu * mu;
        red[0] = mu; red[1] = rsqrtf(var + 1e-5f);
    }
    __syncthreads();
    float mu = red[0], rs = red[1];
    float v0 = (a0 - mu) * rs * g[t] + beta[t];
    float v1 = (a1 - mu) * rs * g[t + 256] + beta[t + 256];
    v0 = v0 >= 0.f ? v0 : 0.2f * v0;
    v1 = v1 >= 0.f ? v1 : 0.2f * v1;
    ushort_t h0_ = f2bf(v0), l0_ = f2bf(v0 - bf2f(h0_));
    ushort_t h1_ = f2bf(v1), l1_ = f2bf(v1 - bf2f(h1_));
    st[t] = h0_;        st[256 + t] = h1_;      // hi occupies kp 0..511
    st[512 + t] = l0_;  st[768 + t] = l1_;      // lo occupies kp 512..1023
    __syncthreads();
    if (t < 128) {
        int kp0 = t * 8;
        *(us8*)(h0big + swz_idx(rb, r, kp0, 16)) = *(const us8*)(st + kp0);
    }
}

// ================= layer-1 aggregation: WAVE per node, 4-edge pipelined =================
// Lane owns 8 contiguous cols (16B gather loads). 4 edges' loads issued before any
// dependent math -> ~2x loads in flight vs round 14 (L3-latency hiding).
// den is complete per lane (per-lane exp over ALL edges) — no cross-lane reduce.
__global__ __launch_bounds__(256) void k_agg1wave(
    const int* __restrict__ csrc, const int* __restrict__ off,
    const ushort_t* __restrict__ h1b,
    const float* __restrict__ aS, const float* __restrict__ aD,
    const float* __restrict__ b1, const float* __restrict__ bnm,
    const float* __restrict__ bnv, const float* __restrict__ bng,
    const float* __restrict__ bnb, ushort_t* __restrict__ h2b)
{
    int t = threadIdx.x;
    int n = blockIdx.x * 4 + (t >> 6);
    int lane = t & 63;
    if (n >= N_NODES) return;
    int j0 = lane * 8;                     // this lane's 8 columns
    int hA = lane >> 3;                    // head of those columns
    float adn = aD[n * NHEAD + hA];
    int beg = off[n], end = off[n + 1];
    float acc[8];
    #pragma unroll
    for (int q = 0; q < 8; q++) acc[q] = 0.f;
    float den = 0.f;
    int c = beg;
    for (; c + 4 <= end; c += 4) {         // 4 edges in flight
        int s0 = csrc[c], s1 = csrc[c + 1], s2 = csrc[c + 2], s3 = csrc[c + 3];
        float a0 = aS[s0 * NHEAD + hA];
        float a1 = aS[s1 * NHEAD + hA];
        float a2 = aS[s2 * NHEAD + hA];
        float a3 = aS[s3 * NHEAD + hA];
        us8 v0 = *(const us8*)(h1b + (size_t)s0 * DW + j0);
        us8 v1 = *(const us8*)(h1b + (size_t)s1 * DW + j0);
        us8 v2 = *(const us8*)(h1b + (size_t)s2 * DW + j0);
        us8 v3 = *(const us8*)(h1b + (size_t)s3 * DW + j0);
        float l0 = a0 + adn; l0 = l0 >= 0.f ? l0 : 0.2f * l0;
        float l1 = a1 + adn; l1 = l1 >= 0.f ? l1 : 0.2f * l1;
        float l2 = a2 + adn; l2 = l2 >= 0.f ? l2 : 0.2f * l2;
        float l3 = a3 + adn; l3 = l3 >= 0.f ? l3 : 0.2f * l3;
        float w0 = __expf(l0), w1 = __expf(l1), w2 = __expf(l2), w3 = __expf(l3);
        den += (w0 + w1) + (w2 + w3);
        #pragma unroll
        for (int q = 0; q < 8; q++) {
            acc[q] += w0 * bf2f(v0[q]) + w1 * bf2f(v1[q]);
            acc[q] += w2 * bf2f(v2[q]) + w3 * bf2f(v3[q]);
        }
    }
    for (; c < end; ++c) {                 // tail
        int s0 = csrc[c];
        float a0 = aS[s0 * NHEAD + hA];
        us8 v0 = *(const us8*)(h1b + (size_t)s0 * DW + j0);
        float l0 = a0 + adn; l0 = l0 >= 0.f ? l0 : 0.2f * l0;
        float w0 = __expf(l0);
        den += w0;
        #pragma unroll
        for (int q = 0; q < 8; q++) acc[q] += w0 * bf2f(v0[q]);
    }
    // den is complete for this (n, head) — NO cross-lane reduce.
    float rd = den > 0.f ? 1.f / den : 0.f;
    unsigned pk[4];
    #pragma unroll
    for (int q = 0; q < 4; q++) {
        int ja = j0 + 2 * q, jb = ja + 1;
        float va = (acc[2 * q] * rd + b1[ja] - bnm[ja]) * (rsqrtf(bnv[ja] + 1e-5f) * bng[ja]) + bnb[ja];
        float vb = (acc[2 * q + 1] * rd + b1[jb] - bnm[jb]) * (rsqrtf(bnv[jb] + 1e-5f) * bng[jb]) + bnb[jb];
        va = va > 0.f ? va : 0.f;
        vb = vb > 0.f ? vb : 0.f;
        pk[q] = (unsigned)f2bf(va) | ((unsigned)f2bf(vb) << 16);
    }
    *(u32x4*)(h2b + (size_t)n * DW + j0) = (u32x4){pk[0], pk[1], pk[2], pk[3]};
}

// ================= GEMM2 + fused att2 (from h2 bf16) =================
__global__ __launch_bounds__(256) void k_gemm2att(const ushort_t* __restrict__ h2b,
                                                  const float* __restrict__ W2,
                                                  const float* __restrict__ as2,
                                                  const float* __restrict__ ad2,
                                                  float* __restrict__ gout,
                                                  float* __restrict__ aS,
                                                  float* __restrict__ aD) {
    __shared__ float Ws[DW * 16];
    __shared__ float gl[16][16];
    __shared__ float a2[32];
    int t = threadIdx.x;
    for (int i = t; i < DW * 16; i += 256) Ws[i] = W2[i];
    if (t < 16) a2[t] = as2[t];
    else if (t < 32) a2[t] = ad2[t - 16];
    __syncthreads();
    int nb = blockIdx.x * 16;
    int nl = t >> 4, j = t & 15;
    const bf16x8* hr = (const bf16x8*)(h2b + (size_t)(nb + nl) * DW);
    float acc = 0.f;
    for (int ks = 0; ks < DW / 8; ks++) {
        bf16x8 v = hr[ks];
        #pragma unroll
        for (int u = 0; u < 8; u++)
            acc += bf2f((ushort_t)v[u]) * Ws[(ks * 8 + u) * 16 + j];
    }
    gout[(nb + nl) * 16 + j] = acc;
    gl[nl][j] = acc;
    __syncthreads();
    if (j < 8) {
        aS[(nb + nl) * NHEAD + j] = gl[nl][2 * j] * a2[2 * j] + gl[nl][2 * j + 1] * a2[2 * j + 1];
    } else {
        int h = j - 8;
        aD[(nb + nl) * NHEAD + h] = gl[nl][2 * h] * a2[16 + 2 * h] + gl[nl][2 * h + 1] * a2[16 + 2 * h + 1];
    }
}

// ================= layer-2 aggregation, CSR, fused head-mean + b2 =================
__global__ __launch_bounds__(256) void k_agg2csr(
    const int* __restrict__ csrc, const int* __restrict__ off,
    const float* __restrict__ gbuf,
    const float* __restrict__ aS, const float* __restrict__ aD,
    const float* __restrict__ b2, float* __restrict__ outp)
{
    int t = threadIdx.x;
    int n = blockIdx.x * 4 + (t >> 6);
    int lane = t & 63;
    if (n >= N_NODES) return;
    int beg = off[n], end = off[n + 1];
    int j = lane & 15, slot = lane >> 4, h = j >> 1;
    float adn = aD[n * NHEAD + h];
    float acc = 0.f, den = 0.f;
    for (int c = beg + slot; c < end; c += 4) {
        int s = csrc[c];
        float l = aS[s * NHEAD + h] + adn;
        l = l >= 0.f ? l : 0.2f * l;
        float w = __expf(l);
        den += w;
        acc += w * gbuf[s * 16 + j];
    }
    acc += __shfl_down(acc, 16, 64); acc += __shfl_down(acc, 32, 64);
    den += __shfl_down(den, 16, 64); den += __shfl_down(den, 32, 64);
    float v = (lane < 16 && den > 0.f) ? acc / den : 0.f;
    v += __shfl_down(v, 2, 64);
    v += __shfl_down(v, 4, 64);
    v += __shfl_down(v, 8, 64);
    if (lane < 2) outp[n * 2 + lane] = v * 0.125f + b2[lane];
}

extern "C" void kernel_launch(void* const* d_in, const int* in_sizes, int n_in,
                              void* d_out, int out_size, void* d_ws, size_t ws_size,
                              hipStream_t stream) {
    const float* x    = (const float*)d_in[0];
    const int*   ei   = (const int*)d_in[1];
    const float* ftW  = (const float*)d_in[2];
    const float* ftb  = (const float*)d_in[3];
    const float* lng  = (const float*)d_in[4];
    const float* lnb  = (const float*)d_in[5];
    const float* W1   = (const float*)d_in[6];
    const float* as1  = (const float*)d_in[7];
    const float* ad1  = (const float*)d_in[8];
    const float* b1   = (const float*)d_in[9];
    const float* bng  = (const float*)d_in[10];
    const float* bnb  = (const float*)d_in[11];
    const float* bnm  = (const float*)d_in[12];
    const float* bnv  = (const float*)d_in[13];
    const float* W2   = (const float*)d_in[14];
    const float* as2  = (const float*)d_in[15];
    const float* ad2  = (const float*)d_in[16];
    const float* b2   = (const float*)d_in[17];
    float* out = (float*)d_out;

    // ---- workspace (float offsets), lifetime-aliased, ~60.2 MB ----
    float* F = (float*)d_ws;
    ushort_t* Ax    = (ushort_t*)(F + 0);          // dead after ft GEMM
    float*    gbuf  = F + 0;                       // 160,000 f
    ushort_t* Bx    = (ushort_t*)(F + 1294336);
    ushort_t* B1    = (ushort_t*)(F + 1359872);
    float*    hpre  = F + 1622016;                 // dead after LN
    ushort_t* h2b   = (ushort_t*)(F + 1622016);    // written by agg1wave
    ushort_t* h0big = (ushort_t*)(F + 6799360);
    ushort_t* h1b   = (ushort_t*)(F + 11976704);
    float*    aS1   = F + 14536704;
    float*    aD1   = F + 14616704;
    float*    aS2   = F + 14696704;
    float*    aD2   = F + 14776704;
    int* cnt        = (int*)(F + 14856704);
    int* cursor     = (int*)(F + 14866704);
    int* off        = (int*)(F + 14876704);
    int* csrc       = (int*)(F + 14886705);

    // 1. merged prep (Ax-vec + Bx + B1 + zero)
    k_prep<<<1952, 256, 0, stream>>>(x, ftW, W1, Ax, Bx, B1, cnt, cursor);
    // 2. ft GEMM (K'=256) + CSR count
    k_tgemm<4, false, 1><<<GEMM_BLKS + 313, 512, 0, stream>>>(
        Ax, Bx, hpre, nullptr, nullptr, nullptr, nullptr, nullptr,
        ei, cnt, nullptr, nullptr, nullptr);
    // 3. LN -> h0big (K'=1024 [hi|lo], vectorized) + CSR scan
    k_ln_scan<<<MPAD + 1, 256, 0, stream>>>(hpre, ftb, lng, lnb, h0big, cnt, off);
    // 4. GEMM1 (K'=1024) + fused att-dots + CSR scatter
    k_tgemm<16, true, 2><<<GEMM_BLKS + 313, 512, 0, stream>>>(
        h0big, B1, nullptr, h1b, as1, ad1, aS1, aD1,
        ei, nullptr, off, cursor, csrc);
    // 5. layer-1 aggregation: wave per node, 4-edge pipelined (fused bias+BN+ReLU -> bf16 h2)
    k_agg1wave<<<(N_NODES + 3) / 4, 256, 0, stream>>>(
        csrc, off, h1b, aS1, aD1, b1, bnm, bnv, bng, bnb, h2b);
    // 6. GEMM2 + fused att2
    k_gemm2att<<<N_NODES / 16, 256, 0, stream>>>(h2b, W2, as2, ad2, gbuf, aS2, aD2);
    // 7. layer-2 aggregation (fused head-mean + b2)
    k_agg2csr<<<(N_NODES + 3) / 4, 256, 0, stream>>>(csrc, off, gbuf, aS2, aD2, b2, out);
}